// Round 20
// baseline (115.648 us; speedup 1.0000x reference)
//
#include <hip/hip_runtime.h>
#include <hip/hip_bf16.h>

#define B_ 8
#define S_ 1024
#define D_ 1024
#define H_ 16
#define DK_ 64
#define BH_ (B_ * H_)
#define NQ 8
#define QTASK 256   // tasks per queue: 16 bh x 16 segs
#define NPERS 768

typedef float f32x4 __attribute__((ext_vector_type(4)));
typedef short s16x8 __attribute__((ext_vector_type(8)));
typedef short s16x4 __attribute__((ext_vector_type(4)));

// hardware transcendentals: v_exp_f32 computes 2^x
#define EXP2F(x) __builtin_amdgcn_exp2f(x)
#define LOG2E 1.44269504088896f

// fp32 -> bf16 (RNE), manual bit version (prep kernels)
static __device__ __forceinline__ short f2b(float f) {
  unsigned u = __builtin_bit_cast(unsigned, f);
  u = u + 0x7FFFu + ((u >> 16) & 1u);
  return (short)(u >> 16);
}
// fp32 -> bf16 via intrinsic
static __device__ __forceinline__ short f2bn(float f) {
  __hip_bfloat16 h = __float2bfloat16(f);
  return __builtin_bit_cast(short, h);
}

static __device__ __forceinline__ int slotf(int g, int e) {
  return (e < 4) ? (4 * g + e) : (16 + 4 * g + (e - 4));
}

// ============================ PREP KERNELS =================================

// K f32 [b][s][d] -> bf16 [b][h][s][dk]
__global__ __launch_bounds__(256) void prep_k(const float* __restrict__ k,
                                              short* __restrict__ kb) {
  const int bid = blockIdx.x;  // 512
  const int s0 = (bid & 63) * 16;
  const int b = bid >> 6;
  const int tid = threadIdx.x;
#pragma unroll
  for (int it = 0; it < 8; ++it) {
    int li = it * 256 + tid;
    int s = s0 + (li >> 7);
    int ch = li & 127;
    int h = ch >> 3;
    int dk0 = (ch & 7) * 8;
    const float* src = k + ((size_t)(b * S_ + s)) * D_ + ch * 8;
    s16x8 o;
#pragma unroll
    for (int e = 0; e < 8; ++e) o[e] = f2b(src[e]);
    *(s16x8*)(kb + ((size_t)((b * H_ + h) * S_ + s)) * DK_ + dk0) = o;
  }
}

// V1/V2 f32 -> bf16 B-fragment layout [bh][jt32][db][lane][8] + column sums
__global__ __launch_bounds__(256) void prep_v(const float* __restrict__ v1,
                                              const float* __restrict__ v2,
                                              short* __restrict__ v1f,
                                              short* __restrict__ v2f,
                                              float* __restrict__ vs) {
  const int bid = blockIdx.x;  // 512
  const int sg = bid & 3;
  const int h = (bid >> 2) & 15;
  const int b = bid >> 6;
  const int tid = threadIdx.x;
  const int db = tid >> 6;
  const int lane = tid & 63;
  const int r = lane & 15;
  const int g = lane >> 4;
  const size_t inbase = (size_t)b * S_ * D_ + h * DK_ + db * 16 + r;
  float s1 = 0.f, s2 = 0.f;
#pragma unroll
  for (int it = 0; it < 8; ++it) {
    int jt = sg * 8 + it;
    int j0 = jt * 32;
    s16x8 o1, o2;
#pragma unroll
    for (int e = 0; e < 8; ++e) {
      int j = j0 + slotf(g, e);
      float a = v1[inbase + (size_t)j * D_];
      float c = v2[inbase + (size_t)j * D_];
      s1 += a;
      s2 += c;
      o1[e] = f2b(a);
      o2[e] = f2b(c);
    }
    size_t off = (((size_t)((b * H_ + h) * 32 + jt) * 4 + db) * 64 + lane) * 8;
    *(s16x8*)(v1f + off) = o1;
    *(s16x8*)(v2f + off) = o2;
  }
  s1 += __shfl_xor(s1, 16);
  s1 += __shfl_xor(s1, 32);
  s2 += __shfl_xor(s2, 16);
  s2 += __shfl_xor(s2, 32);
  if (g == 0) {
    int dd = db * 16 + r;
    atomicAdd(&vs[(size_t)b * D_ + h * DK_ + dd], s1);
    atomicAdd(&vs[(size_t)(B_ + b) * D_ + h * DK_ + dd], s2);
  }
}

// ============================ MAIN ATTENTION ================================
// R19 post-mortem: per-XCD queues recovered occupancy+partial locality
// (88us, FETCH 105MB). Residual: seg-major order makes each XCD's 96 blocks
// span all 16 bh (6MB > 4MB L2). This round: BH-MAJOR queue order — 16
// consecutive tasks share one bh (segs 15..0 heavy-first within bh) ->
// concurrent working set ~6 bh ~= 2.3MB <= L2. Everything else unchanged.
__global__ __launch_bounds__(256, 3) void attn_series2r(
    const float* __restrict__ q, const short* __restrict__ kb,
    const short* __restrict__ v1f, const short* __restrict__ v2f,
    const int* __restrict__ cm, const float* __restrict__ vs,
    unsigned* __restrict__ counters, float* __restrict__ out) {
  const int tid = threadIdx.x;
  const int wid = tid >> 6;
  const int lane = tid & 63;
  const int r = lane & 15;
  const int g = lane >> 4;

  // physical XCD id; perf hint only (work-stealing keeps correctness)
  unsigned xcc = 0;
  asm volatile("s_getreg_b32 %0, hwreg(HW_REG_XCC_ID)" : "=s"(xcc));
  const int xq = (int)(xcc & 7u);

  // LDS: 2 buffers x {K 4KB (swizzled) | V1 4KB | V2 4KB}
  __shared__ __align__(16) char sbuf[2][12288];
  __shared__ unsigned cmw[32];
  __shared__ int taskS;

  const int srow = tid >> 3;  // staging K row 0..31
  const int sch = tid & 7;    // staging K chunk 0..7

#define SLK(reg, jtv) reg = *(const s16x8*)(kbh + (size_t)(jtv)*2048 + tid * 8);
#define SLV(d1, d2, jtv)                                           \
  {                                                                \
    d1 = *(const s16x8*)(v1bh + (size_t)(jtv)*2048 + tid * 8);     \
    d2 = *(const s16x8*)(v2bh + (size_t)(jtv)*2048 + tid * 8);     \
  }
#define SWK(buf, reg) \
  *(s16x8*)((buf) + srow * 128 + ((sch ^ (srow & 7)) * 16)) = reg;
#define SWV(buf, d1, d2)                        \
  {                                             \
    *(s16x8*)((buf) + 4096 + tid * 16) = d1;    \
    *(s16x8*)((buf) + 8192 + tid * 16) = d2;    \
  }
#define KFRAG(sK, row, quad) \
  (*(const s16x8*)((sK) + (row)*128 + (((quad) ^ ((row)&7)) * 16)))

  float* out1 = out;
  float* out2 = out + (size_t)B_ * S_ * D_;

  for (int qi = 0; qi < NQ; ++qi) {
    const int qq = (xq + qi) & 7;
    for (;;) {
      __syncthreads();  // previous task's LDS reads + taskS read complete
      if (tid == 0) taskS = (int)atomicAdd(&counters[qq * 64], 1u);
      __syncthreads();
      const int task = taskS;
      if (task >= QTASK) break;

      // bh-major order: 16 consecutive tasks share one bh; heavy-first segs
      const int seg = 15 - (task & 15);
      const int bh = (task >> 4) * 8 + qq;
      const int b = bh >> 4, h = bh & 15;

      const int qw = seg * 64 + wid * 16;  // this wave's 16 q-rows
      const int iq = qw + r;
      const int njt = 2 * seg + 2;         // 32-wide tiles (block-uniform)

      {
        const int* cmb = cm + b * S_;
#pragma unroll
        for (int it = 0; it < 4; ++it) {
          unsigned long long m = __ballot(cmb[it * 256 + tid] == 1);
          if (lane == 0) {
            int w0 = it * 8 + wid * 2;
            cmw[w0] = (unsigned)m;
            cmw[w0 + 1] = (unsigned)(m >> 32);
          }
        }
      }

      // Q fragments, pre-scaled by log2e/sqrt(dk) -> log2-domain scores
      const float qscale = 0.125f * LOG2E;
      s16x8 qf0, qf1;
      {
        const float* qp = q + ((size_t)(b * S_ + qw + r)) * D_ + h * DK_;
#pragma unroll
        for (int e = 0; e < 8; ++e) qf0[e] = f2bn(qp[8 * g + e] * qscale);
#pragma unroll
        for (int e = 0; e < 8; ++e) qf1[e] = f2bn(qp[32 + 8 * g + e] * qscale);
      }

      const short* kbh = kb + (size_t)bh * S_ * DK_;
      const short* v1bh = v1f + (size_t)bh * 32 * 2048;
      const short* v2bh = v2f + (size_t)bh * 32 * 2048;

      // accumulators: term k=1..2 for V1 and V2
      f32x4 a11[4], a12[4], a21[4], a22[4];
#pragma unroll
      for (int d0 = 0; d0 < 4; ++d0) {
        a11[d0] = (f32x4){0.f, 0.f, 0.f, 0.f};
        a12[d0] = (f32x4){0.f, 0.f, 0.f, 0.f};
        a21[d0] = (f32x4){0.f, 0.f, 0.f, 0.f};
        a22[d0] = (f32x4){0.f, 0.f, 0.f, 0.f};
      }
      float Z1 = 0.f, T1 = 0.f, T2 = 0.f;

      {
        s16x8 rk, rv1, rv2;
        SLK(rk, 0);
        SLV(rv1, rv2, 0);
        SWK(sbuf[0], rk);
        SWV(sbuf[0], rv1, rv2);
        __syncthreads();  // cmw + buf0 ready
        for (int jt = 0; jt < njt; ++jt) {
          const int jb = jt * 32;
          const char* sB = sbuf[jt & 1];
          const bool pf = (jt + 1 < njt);
          s16x8 rk2, rv12, rv22;
          if (pf) {
            SLK(rk2, jt + 1);
            SLV(rv12, rv22, jt + 1);
          }
          if (jb < qw + 16) {  // tile has work for this wave
            s16x8 k00 = KFRAG(sB, r, g);
            s16x8 k01 = KFRAG(sB, r, 4 + g);
            s16x8 k10 = KFRAG(sB, 16 + r, g);
            s16x8 k11 = KFRAG(sB, 16 + r, 4 + g);
            f32x4 s0 = {0.f, 0.f, 0.f, 0.f}, s1 = {0.f, 0.f, 0.f, 0.f};
            s0 = __builtin_amdgcn_mfma_f32_16x16x32_bf16(k00, qf0, s0, 0, 0, 0);
            s0 = __builtin_amdgcn_mfma_f32_16x16x32_bf16(k01, qf1, s0, 0, 0, 0);
            s1 = __builtin_amdgcn_mfma_f32_16x16x32_bf16(k10, qf0, s1, 0, 0, 0);
            s1 = __builtin_amdgcn_mfma_f32_16x16x32_bf16(k11, qf1, s1, 0, 0, 0);
            const unsigned cw = cmw[jt];
            const bool cb = (jb + 32 > qw);  // tile crosses diagonal
            float w1[8], w2[8];
#pragma unroll
            for (int s2 = 0; s2 < 2; ++s2) {
              f32x4 sv = s2 ? s1 : s0;
#pragma unroll
              for (int e = 0; e < 4; ++e) {
                int sl = s2 * 16 + 4 * g + e;
                int j = jb + sl;
                float pe = EXP2F(sv[e]);          // exp(s_j), unnormalized
                if (cb) pe = (j < iq) ? pe : 0.f; // causal (first softmax)
                Z1 += pe;
                float pm = ((cw >> sl) & 1u) ? 0.f : pe;  // cm mask
                float pm2 = pm * pm;
                T1 += pm;
                T2 += pm2;
                int o = s2 * 4 + e;
                w1[o] = pm;
                w2[o] = pm2;
              }
            }
            s16x8 wa1, wa2;
#pragma unroll
            for (int e = 0; e < 8; ++e) {
              wa1[e] = f2bn(w1[e]);
              wa2[e] = f2bn(w2[e]);
            }
            s16x8 vb1[4], vb2[4];
#pragma unroll
            for (int db = 0; db < 4; ++db) {
              vb1[db] = *(const s16x8*)(sB + 4096 + (db * 64 + lane) * 16);
              vb2[db] = *(const s16x8*)(sB + 8192 + (db * 64 + lane) * 16);
            }
#pragma unroll
            for (int db = 0; db < 4; ++db) {
              a11[db] = __builtin_amdgcn_mfma_f32_16x16x32_bf16(wa1, vb1[db], a11[db], 0, 0, 0);
              a21[db] = __builtin_amdgcn_mfma_f32_16x16x32_bf16(wa1, vb2[db], a21[db], 0, 0, 0);
              a12[db] = __builtin_amdgcn_mfma_f32_16x16x32_bf16(wa2, vb1[db], a12[db], 0, 0, 0);
              a22[db] = __builtin_amdgcn_mfma_f32_16x16x32_bf16(wa2, vb2[db], a22[db], 0, 0, 0);
            }
          }
          if (pf) {
            SWK(sbuf[(jt + 1) & 1], rk2);
            SWV(sbuf[(jt + 1) & 1], rv12, rv22);
          }
          __syncthreads();
        }
      }

      // reduce per-column sums across the 4 g-groups (lane's col = r)
      Z1 += __shfl_xor(Z1, 16);
      Z1 += __shfl_xor(Z1, 32);
      T1 += __shfl_xor(T1, 16);
      T1 += __shfl_xor(T1, 32);
      T2 += __shfl_xor(T2, 16);
      T2 += __shfl_xor(T2, 32);

      const float iz = (Z1 > 0.f) ? (1.f / Z1) : 0.f;  // row 0: terms vanish
      const float f1 = iz;
      const float f2 = 0.5f * iz * iz;
      const float Z2 = (float)S_ + T1 * f1 + T2 * f2;
      const float izz = 1.f / Z2;
      const float g1v = f1 * izz;
      const float g2v = f2 * izz;
      const float gcv = izz;

      const float* vs1 = vs + (size_t)b * D_ + h * DK_;
      const float* vs2 = vs + (size_t)(B_ + b) * D_ + h * DK_;

#pragma unroll
      for (int e = 0; e < 4; ++e) {
        float gg1 = __shfl(g1v, 4 * g + e);  // lane 4g+e holds col 4g+e
        float gg2 = __shfl(g2v, 4 * g + e);
        float ggc = __shfl(gcv, 4 * g + e);
        int io = qw + 4 * g + e;
        bool zero = (io == 0);  // reference zeroes p row 0
        size_t ro = ((size_t)(b * S_) + io) * D_ + h * DK_;
#pragma unroll
        for (int db = 0; db < 4; ++db) {
          int dd = db * 16 + r;
          float o1 = a11[db][e] * gg1 + a12[db][e] * gg2 + vs1[dd] * ggc;
          float o2 = a21[db][e] * gg1 + a22[db][e] * gg2 + vs2[dd] * ggc;
          out1[ro + dd] = zero ? 0.f : o1;
          out2[ro + dd] = zero ? 0.f : o2;
        }
      }
    }
  }
#undef SLK
#undef SLV
#undef SWK
#undef SWV
#undef KFRAG
}

// ====================== FALLBACK (needs only 64KB ws) =======================

__global__ __launch_bounds__(256) void vsum_kernel(const float* __restrict__ v1,
                                                   const float* __restrict__ v2,
                                                   float* __restrict__ vs) {
  int bid = blockIdx.x;
  int sc = bid & 7, dc = (bid >> 3) & 3, b = bid >> 5;
  int d = dc * 256 + threadIdx.x;
  const float* p1 = v1 + ((size_t)b * S_ + sc * 128) * D_ + d;
  const float* p2 = v2 + ((size_t)b * S_ + sc * 128) * D_ + d;
  float s1 = 0.f, s2 = 0.f;
  for (int j = 0; j < 128; ++j) {
    s1 += p1[(size_t)j * D_];
    s2 += p2[(size_t)j * D_];
  }
  atomicAdd(&vs[b * D_ + d], s1);
  atomicAdd(&vs[B_ * D_ + b * D_ + d], s2);
}

__global__ __launch_bounds__(256) void dualattn_fallback(
    const float* __restrict__ q, const float* __restrict__ k,
    const float* __restrict__ v1, const float* __restrict__ v2,
    const int* __restrict__ cm, const float* __restrict__ vs,
    float* __restrict__ out) {
  const int bid = blockIdx.x;
  const int qt = bid & 15;
  const int h = (bid >> 4) & 15;
  const int b = bid >> 8;
  const int tid = threadIdx.x;
  const int wid = tid >> 6;
  const int lane = tid & 63;
  const int r = lane & 15;
  const int g = lane >> 4;
  const int qw = qt * 64 + wid * 16;
  const int iq = qw + r;

  __shared__ __align__(16) char kbuf[32 * 128];
  __shared__ __align__(16) char vtb1[64 * 64];
  __shared__ __align__(16) char vtb2[64 * 64];
  __shared__ unsigned cmw[32];

  {
    const int* cmb = cm + b * S_;
#pragma unroll
    for (int it = 0; it < 4; ++it) {
      int c = cmb[it * 256 + tid];
      unsigned long long m = __ballot(c == 1);
      if (lane == 0) {
        int w0 = (it * 256 + wid * 64) >> 5;
        cmw[w0] = (unsigned)m;
        cmw[w0 + 1] = (unsigned)(m >> 32);
      }
    }
  }

  s16x8 qf0, qf1;
  {
    const float* qp = q + ((size_t)(b * S_) + qw + r) * D_ + h * DK_;
#pragma unroll
    for (int e = 0; e < 8; ++e) qf0[e] = f2b(qp[8 * g + e] * 0.125f);
#pragma unroll
    for (int e = 0; e < 8; ++e) qf1[e] = f2b(qp[32 + 8 * g + e] * 0.125f);
  }

  const int njt = 2 * qt + 2;
  const float* kbase = k + (size_t)(b * S_) * D_ + h * DK_;
  const float* v1base = v1 + (size_t)(b * S_) * D_ + h * DK_;
  const float* v2base = v2 + (size_t)(b * S_) * D_ + h * DK_;
  const int srow = tid >> 3;
  const int sch = tid & 7;

  float m1 = -INFINITY, Z1 = 0.f;
  for (int jt = 0; jt < njt; ++jt) {
    const int jbase = jt * 32;
    __syncthreads();
    {
      const float* kr = kbase + (size_t)(jbase + srow) * D_ + sch * 8;
      s16x8 pk;
#pragma unroll
      for (int e = 0; e < 8; ++e) pk[e] = f2b(kr[e]);
      *(s16x8*)(kbuf + srow * 128 + ((sch ^ (srow & 7)) * 16)) = pk;
    }
    __syncthreads();
    if (jbase < qw + 16) {
#pragma unroll
      for (int sub = 0; sub < 2; ++sub) {
        const int jsb = jbase + sub * 16;
        if (jsb < qw + 16) {
          const int row = sub * 16 + r;
          s16x8 ka0 = *(const s16x8*)(kbuf + row * 128 + ((g ^ (row & 7)) * 16));
          s16x8 ka1 = *(const s16x8*)(kbuf + row * 128 + (((4 + g) ^ (row & 7)) * 16));
          f32x4 sv = {0.f, 0.f, 0.f, 0.f};
          sv = __builtin_amdgcn_mfma_f32_16x16x32_bf16(ka0, qf0, sv, 0, 0, 0);
          sv = __builtin_amdgcn_mfma_f32_16x16x32_bf16(ka1, qf1, sv, 0, 0, 0);
          float tm = m1;
#pragma unroll
          for (int e = 0; e < 4; ++e) {
            int j = jsb + 4 * g + e;
            if (j < iq) tm = fmaxf(tm, sv[e]);
          }
          if (tm > m1) { Z1 *= __expf(m1 - tm); m1 = tm; }
#pragma unroll
          for (int e = 0; e < 4; ++e) {
            int j = jsb + 4 * g + e;
            if (j < iq) Z1 += __expf(sv[e] - tm);
          }
        }
      }
    }
  }
#pragma unroll
  for (int off = 16; off < 64; off <<= 1) {
    float mo = __shfl_xor(m1, off);
    float zo = __shfl_xor(Z1, off);
    float mn = fmaxf(m1, mo);
    if (mn > -INFINITY) {
      Z1 = Z1 * __expf(m1 - mn) + zo * __expf(mo - mn);
      m1 = mn;
    }
  }
  float z1i;
  if (m1 > -INFINITY) { z1i = 1.f / Z1; }
  else { z1i = 0.f; m1 = 0.f; }

  f32x4 acc1[4], acc2[4];
#pragma unroll
  for (int d0 = 0; d0 < 4; ++d0) {
    acc1[d0] = (f32x4){0.f, 0.f, 0.f, 0.f};
    acc2[d0] = (f32x4){0.f, 0.f, 0.f, 0.f};
  }
  float wsum = 0.f;

  for (int jt = 0; jt < njt; ++jt) {
    const int jbase = jt * 32;
    __syncthreads();
    {
      const float* kr = kbase + (size_t)(jbase + srow) * D_ + sch * 8;
      s16x8 pk;
#pragma unroll
      for (int e = 0; e < 8; ++e) pk[e] = f2b(kr[e]);
      *(s16x8*)(kbuf + srow * 128 + ((sch ^ (srow & 7)) * 16)) = pk;
      const float* v1r = v1base + (size_t)(jbase + srow) * D_ + sch * 8;
      const float* v2r = v2base + (size_t)(jbase + srow) * D_ + sch * 8;
#pragma unroll
      for (int e = 0; e < 8; ++e) {
        int dd = sch * 8 + e;
        int off = dd * 64 + (((srow >> 2) ^ (dd & 7)) * 8) + (srow & 3) * 2;
        *(short*)(vtb1 + off) = f2b(v1r[e]);
        *(short*)(vtb2 + off) = f2b(v2r[e]);
      }
    }
    __syncthreads();
    if (jbase < qw + 16) {
      const unsigned cmword = cmw[jbase >> 5];
      float w[8];
#pragma unroll
      for (int sub = 0; sub < 2; ++sub) {
        const int jsb = jbase + sub * 16;
        if (jsb < qw + 16) {
          const int row = sub * 16 + r;
          s16x8 ka0 = *(const s16x8*)(kbuf + row * 128 + ((g ^ (row & 7)) * 16));
          s16x8 ka1 = *(const s16x8*)(kbuf + row * 128 + (((4 + g) ^ (row & 7)) * 16));
          f32x4 sv = {0.f, 0.f, 0.f, 0.f};
          sv = __builtin_amdgcn_mfma_f32_16x16x32_bf16(ka0, qf0, sv, 0, 0, 0);
          sv = __builtin_amdgcn_mfma_f32_16x16x32_bf16(ka1, qf1, sv, 0, 0, 0);
#pragma unroll
          for (int e = 0; e < 4; ++e) {
            int j = jsb + 4 * g + e;
            float x = 0.f;
            if (j < iq && !((cmword >> (j & 31)) & 1u)) {
              float p = __expf(sv[e] - m1) * z1i;
              x = __expf(p) - 1.f;
            }
            w[sub * 4 + e] = x;
            wsum += x;
          }
        } else {
#pragma unroll
          for (int e = 0; e < 4; ++e) w[sub * 4 + e] = 0.f;
        }
      }
      s16x8 wa;
#pragma unroll
      for (int e = 0; e < 8; ++e) wa[e] = f2b(w[e]);
#pragma unroll
      for (int db = 0; db < 4; ++db) {
        const int dd = db * 16 + r;
        const int off0 = dd * 64 + ((g ^ (dd & 7)) * 8);
        const int off1 = dd * 64 + (((4 + g) ^ (dd & 7)) * 8);
        s16x4 lo1 = *(const s16x4*)(vtb1 + off0);
        s16x4 hi1 = *(const s16x4*)(vtb1 + off1);
        s16x8 vb1 = __builtin_shufflevector(lo1, hi1, 0, 1, 2, 3, 4, 5, 6, 7);
        acc1[db] = __builtin_amdgcn_mfma_f32_16x16x32_bf16(wa, vb1, acc1[db], 0, 0, 0);
        s16x4 lo2 = *(const s16x4*)(vtb2 + off0);
        s16x4 hi2 = *(const s16x4*)(vtb2 + off1);
        s16x8 vb2 = __builtin_shufflevector(lo2, hi2, 0, 1, 2, 3, 4, 5, 6, 7);
        acc2[db] = __builtin_amdgcn_mfma_f32_16x16x32_bf16(wa, vb2, acc2[db], 0, 0, 0);
      }
    }
  }

  wsum += __shfl_xor(wsum, 16);
  wsum += __shfl_xor(wsum, 32);
  const float z2 = (float)S_ + wsum;

  float* out1 = out;
  float* out2 = out + (size_t)B_ * S_ * D_;
#pragma unroll
  for (int e = 0; e < 4; ++e) {
    float z2e = __shfl(z2, 4 * g + e);
    float inv = 1.f / z2e;
    int io = qw + 4 * g + e;
    bool zero = (io == 0);
    size_t ro = ((size_t)(b * S_) + io) * D_ + h * DK_;
#pragma unroll
    for (int db = 0; db < 4; ++db) {
      int dd = db * 16 + r;
      float c1 = vs[(size_t)b * D_ + h * DK_ + dd];
      float c2 = vs[(size_t)(B_ + b) * D_ + h * DK_ + dd];
      out1[ro + dd] = zero ? 0.f : (acc1[db][e] + c1) * inv;
      out2[ro + dd] = zero ? 0.f : (acc2[db][e] + c2) * inv;
    }
  }
}

// ============================================================================

extern "C" void kernel_launch(void* const* d_in, const int* in_sizes, int n_in,
                              void* d_out, int out_size, void* d_ws, size_t ws_size,
                              hipStream_t stream) {
  (void)in_sizes; (void)n_in; (void)out_size;
  const float* q = (const float*)d_in[0];
  const float* k = (const float*)d_in[1];
  const float* v1 = (const float*)d_in[2];
  const float* v2 = (const float*)d_in[3];
  const int* cm = (const int*)d_in[4];
  float* outp = (float*)d_out;

  const size_t VS_BYTES = 2 * B_ * D_ * sizeof(float);  // 64 KB
  const size_t CTR_BYTES = NQ * 64 * sizeof(unsigned);  // 8 queues, 256B apart
  const size_t FRAG_SHORTS = (size_t)BH_ * S_ * DK_;    // 8M shorts
  const size_t FRAG_BYTES = FRAG_SHORTS * 2;            // 16 MB
  const size_t NEED = VS_BYTES + CTR_BYTES + 3 * FRAG_BYTES;

  float* vs = (float*)d_ws;
  (void)hipMemsetAsync(d_ws, 0, VS_BYTES + CTR_BYTES, stream);

  if (ws_size >= NEED) {
    unsigned* counters = (unsigned*)((char*)d_ws + VS_BYTES);
    short* kb = (short*)((char*)d_ws + VS_BYTES + CTR_BYTES);
    short* v1f = kb + FRAG_SHORTS;
    short* v2f = v1f + FRAG_SHORTS;
    prep_k<<<B_ * (S_ / 16), 256, 0, stream>>>(k, kb);
    prep_v<<<B_ * H_ * 4, 256, 0, stream>>>(v1, v2, v1f, v2f, vs);
    attn_series2r<<<NPERS, 256, 0, stream>>>(q, kb, v1f, v2f, cm, vs, counters,
                                             outp);
  } else {
    vsum_kernel<<<256, 256, 0, stream>>>(v1, v2, vs);
    dualattn_fallback<<<B_ * H_ * 16, 256, 0, stream>>>(q, k, v1, v2, cm, vs, outp);
  }
}

// Round 21
// 101.998 us; speedup vs baseline: 1.1338x; 1.1338x over previous
//
#include <hip/hip_runtime.h>
#include <hip/hip_bf16.h>

#define B_ 8
#define S_ 1024
#define D_ 1024
#define H_ 16
#define DK_ 64
#define BH_ (B_ * H_)
#define NQ 8
#define QTASK 256   // tasks per queue: 16 bh x 16 segs
#define NPERS 768

typedef float f32x4 __attribute__((ext_vector_type(4)));
typedef short s16x8 __attribute__((ext_vector_type(8)));
typedef short s16x4 __attribute__((ext_vector_type(4)));

// hardware transcendentals: v_exp_f32 computes 2^x
#define EXP2F(x) __builtin_amdgcn_exp2f(x)
#define LOG2E 1.44269504088896f

// fp32 -> bf16 (RNE), manual bit version (prep kernels)
static __device__ __forceinline__ short f2b(float f) {
  unsigned u = __builtin_bit_cast(unsigned, f);
  u = u + 0x7FFFu + ((u >> 16) & 1u);
  return (short)(u >> 16);
}
// fp32 -> bf16 via intrinsic
static __device__ __forceinline__ short f2bn(float f) {
  __hip_bfloat16 h = __float2bfloat16(f);
  return __builtin_bit_cast(short, h);
}

static __device__ __forceinline__ int slotf(int g, int e) {
  return (e < 4) ? (4 * g + e) : (16 + 4 * g + (e - 4));
}

// ============================ PREP KERNELS =================================

// K f32 [b][s][d] -> bf16 [b][h][s][dk]
__global__ __launch_bounds__(256) void prep_k(const float* __restrict__ k,
                                              short* __restrict__ kb) {
  const int bid = blockIdx.x;  // 512
  const int s0 = (bid & 63) * 16;
  const int b = bid >> 6;
  const int tid = threadIdx.x;
#pragma unroll
  for (int it = 0; it < 8; ++it) {
    int li = it * 256 + tid;
    int s = s0 + (li >> 7);
    int ch = li & 127;
    int h = ch >> 3;
    int dk0 = (ch & 7) * 8;
    const float* src = k + ((size_t)(b * S_ + s)) * D_ + ch * 8;
    s16x8 o;
#pragma unroll
    for (int e = 0; e < 8; ++e) o[e] = f2b(src[e]);
    *(s16x8*)(kb + ((size_t)((b * H_ + h) * S_ + s)) * DK_ + dk0) = o;
  }
}

// V1/V2 f32 -> bf16 B-fragment layout [bh][jt32][db][lane][8] with cm-masked
// rows ZEROED (so PV MFMAs need no in-loop cm mask), + UNMASKED column sums.
__global__ __launch_bounds__(256) void prep_v(const float* __restrict__ v1,
                                              const float* __restrict__ v2,
                                              const int* __restrict__ cm,
                                              short* __restrict__ v1f,
                                              short* __restrict__ v2f,
                                              float* __restrict__ vs) {
  const int bid = blockIdx.x;  // 512
  const int sg = bid & 3;
  const int h = (bid >> 2) & 15;
  const int b = bid >> 6;
  const int tid = threadIdx.x;
  const int db = tid >> 6;
  const int lane = tid & 63;
  const int r = lane & 15;
  const int g = lane >> 4;
  const size_t inbase = (size_t)b * S_ * D_ + h * DK_ + db * 16 + r;
  const int* cmb = cm + b * S_;
  float s1 = 0.f, s2 = 0.f;
#pragma unroll
  for (int it = 0; it < 8; ++it) {
    int jt = sg * 8 + it;
    int j0 = jt * 32;
    s16x8 o1, o2;
#pragma unroll
    for (int e = 0; e < 8; ++e) {
      int j = j0 + slotf(g, e);
      float a = v1[inbase + (size_t)j * D_];
      float c = v2[inbase + (size_t)j * D_];
      s1 += a;       // baseline sums are over ALL rows (unmasked)
      s2 += c;
      bool msk = (cmb[j] == 1);
      o1[e] = msk ? (short)0 : f2b(a);
      o2[e] = msk ? (short)0 : f2b(c);
    }
    size_t off = (((size_t)((b * H_ + h) * 32 + jt) * 4 + db) * 64 + lane) * 8;
    *(s16x8*)(v1f + off) = o1;
    *(s16x8*)(v2f + off) = o2;
  }
  s1 += __shfl_xor(s1, 16);
  s1 += __shfl_xor(s1, 32);
  s2 += __shfl_xor(s2, 16);
  s2 += __shfl_xor(s2, 32);
  if (g == 0) {
    int dd = db * 16 + r;
    atomicAdd(&vs[(size_t)b * D_ + h * DK_ + dd], s1);
    atomicAdd(&vs[(size_t)(B_ + b) * D_ + h * DK_ + dd], s2);
  }
}

// ============================ MAIN ATTENTION ================================
// R20 post-mortem: bh-major fixed locality but broke LPT (97us). Revert to
// R19 seg-major order (best: 88.5us). New this round: VALU cut —
// (1) cm applied offline in prep_v (zeroed V rows) -> no in-loop cm cndmask;
// (2) Z1/T1/T2 normalizer sums moved to the MFMA pipe (ones-/mask-fragment
// MFMAs, 3/tile), deleting 24 scalar adds + 6 shfl reductions + epilogue
// shfls. Per-tile VALU ~64 -> ~40; MFMA 8 -> 11 (pipe at 20% util).
__global__ __launch_bounds__(256, 3) void attn_series2s(
    const float* __restrict__ q, const short* __restrict__ kb,
    const short* __restrict__ v1f, const short* __restrict__ v2f,
    const int* __restrict__ cm, const float* __restrict__ vs,
    unsigned* __restrict__ counters, float* __restrict__ out) {
  const int tid = threadIdx.x;
  const int wid = tid >> 6;
  const int lane = tid & 63;
  const int r = lane & 15;
  const int g = lane >> 4;

  // physical XCD id; perf hint only (work-stealing keeps correctness)
  unsigned xcc = 0;
  asm volatile("s_getreg_b32 %0, hwreg(HW_REG_XCC_ID)" : "=s"(xcc));
  const int xq = (int)(xcc & 7u);

  // LDS: 2 buffers x {K 4KB (swizzled) | V1 4KB | V2 4KB}
  __shared__ __align__(16) char sbuf[2][12288];
  __shared__ unsigned cmw[32];
  __shared__ int taskS;

  const int srow = tid >> 3;  // staging K row 0..31
  const int sch = tid & 7;    // staging K chunk 0..7

#define SLK(reg, jtv) reg = *(const s16x8*)(kbh + (size_t)(jtv)*2048 + tid * 8);
#define SLV(d1, d2, jtv)                                           \
  {                                                                \
    d1 = *(const s16x8*)(v1bh + (size_t)(jtv)*2048 + tid * 8);     \
    d2 = *(const s16x8*)(v2bh + (size_t)(jtv)*2048 + tid * 8);     \
  }
#define SWK(buf, reg) \
  *(s16x8*)((buf) + srow * 128 + ((sch ^ (srow & 7)) * 16)) = reg;
#define SWV(buf, d1, d2)                        \
  {                                             \
    *(s16x8*)((buf) + 4096 + tid * 16) = d1;    \
    *(s16x8*)((buf) + 8192 + tid * 16) = d2;    \
  }
#define KFRAG(sK, row, quad) \
  (*(const s16x8*)((sK) + (row)*128 + (((quad) ^ ((row)&7)) * 16)))

  s16x8 ones;
#pragma unroll
  for (int e = 0; e < 8; ++e) ones[e] = (short)0x3F80;  // bf16 1.0

  float* out1 = out;
  float* out2 = out + (size_t)B_ * S_ * D_;

  for (int qi = 0; qi < NQ; ++qi) {
    const int qq = (xq + qi) & 7;
    for (;;) {
      __syncthreads();  // previous task's LDS reads + taskS read complete
      if (tid == 0) taskS = (int)atomicAdd(&counters[qq * 64], 1u);
      __syncthreads();
      const int task = taskS;
      if (task >= QTASK) break;

      // seg-major (R19, LPT): tasks 0..15 are seg 15 across bh, then seg 14...
      const int seg = 15 - (task >> 4);
      const int bh = (task & 15) * 8 + qq;
      const int b = bh >> 4, h = bh & 15;

      const int qw = seg * 64 + wid * 16;  // this wave's 16 q-rows
      const int iq = qw + r;
      const int njt = 2 * seg + 2;         // 32-wide tiles (block-uniform)

      {
        const int* cmb = cm + b * S_;
#pragma unroll
        for (int it = 0; it < 4; ++it) {
          unsigned long long m = __ballot(cmb[it * 256 + tid] == 1);
          if (lane == 0) {
            int w0 = it * 8 + wid * 2;
            cmw[w0] = (unsigned)m;
            cmw[w0 + 1] = (unsigned)(m >> 32);
          }
        }
      }

      // Q fragments, pre-scaled by log2e/sqrt(dk) -> log2-domain scores
      const float qscale = 0.125f * LOG2E;
      s16x8 qf0, qf1;
      {
        const float* qp = q + ((size_t)(b * S_ + qw + r)) * D_ + h * DK_;
#pragma unroll
        for (int e = 0; e < 8; ++e) qf0[e] = f2bn(qp[8 * g + e] * qscale);
#pragma unroll
        for (int e = 0; e < 8; ++e) qf1[e] = f2bn(qp[32 + 8 * g + e] * qscale);
      }

      const short* kbh = kb + (size_t)bh * S_ * DK_;
      const short* v1bh = v1f + (size_t)bh * 32 * 2048;
      const short* v2bh = v2f + (size_t)bh * 32 * 2048;

      // accumulators: PV terms k=1..2 for V1,V2 + normalizers (MFMA-summed)
      f32x4 a11[4], a12[4], a21[4], a22[4];
#pragma unroll
      for (int d0 = 0; d0 < 4; ++d0) {
        a11[d0] = (f32x4){0.f, 0.f, 0.f, 0.f};
        a12[d0] = (f32x4){0.f, 0.f, 0.f, 0.f};
        a21[d0] = (f32x4){0.f, 0.f, 0.f, 0.f};
        a22[d0] = (f32x4){0.f, 0.f, 0.f, 0.f};
      }
      f32x4 za = {0.f, 0.f, 0.f, 0.f};   // Z1 per q-row 4g+e
      f32x4 t1a = {0.f, 0.f, 0.f, 0.f};  // T1
      f32x4 t2a = {0.f, 0.f, 0.f, 0.f};  // T2

      {
        s16x8 rk, rv1, rv2;
        SLK(rk, 0);
        SLV(rv1, rv2, 0);
        SWK(sbuf[0], rk);
        SWV(sbuf[0], rv1, rv2);
        __syncthreads();  // cmw + buf0 ready
        for (int jt = 0; jt < njt; ++jt) {
          const int jb = jt * 32;
          const char* sB = sbuf[jt & 1];
          const bool pf = (jt + 1 < njt);
          s16x8 rk2, rv12, rv22;
          if (pf) {
            SLK(rk2, jt + 1);
            SLV(rv12, rv22, jt + 1);
          }
          if (jb < qw + 16) {  // tile has work for this wave
            s16x8 k00 = KFRAG(sB, r, g);
            s16x8 k01 = KFRAG(sB, r, 4 + g);
            s16x8 k10 = KFRAG(sB, 16 + r, g);
            s16x8 k11 = KFRAG(sB, 16 + r, 4 + g);
            f32x4 s0 = {0.f, 0.f, 0.f, 0.f}, s1 = {0.f, 0.f, 0.f, 0.f};
            s0 = __builtin_amdgcn_mfma_f32_16x16x32_bf16(k00, qf0, s0, 0, 0, 0);
            s0 = __builtin_amdgcn_mfma_f32_16x16x32_bf16(k01, qf1, s0, 0, 0, 0);
            s1 = __builtin_amdgcn_mfma_f32_16x16x32_bf16(k10, qf0, s1, 0, 0, 0);
            s1 = __builtin_amdgcn_mfma_f32_16x16x32_bf16(k11, qf1, s1, 0, 0, 0);
            const unsigned cw = cmw[jt];
            const bool cb = (jb + 32 > qw);  // tile crosses diagonal
            float w1[8], w2[8];
#pragma unroll
            for (int s2 = 0; s2 < 2; ++s2) {
              f32x4 sv = s2 ? s1 : s0;
#pragma unroll
              for (int e = 0; e < 4; ++e) {
                float pe = EXP2F(sv[e]);  // exp(s_j), unnormalized
                if (cb) {
                  int j = jb + s2 * 16 + 4 * g + e;
                  pe = (j < iq) ? pe : 0.f;  // causal (first softmax)
                }
                int o = s2 * 4 + e;
                w1[o] = pe;
                w2[o] = pe * pe;
              }
            }
            s16x8 wa1, wa2, mf;
#pragma unroll
            for (int o = 0; o < 8; ++o) {
              wa1[o] = f2bn(w1[o]);
              wa2[o] = f2bn(w2[o]);
              int kk = slotf(g, o);  // same k-map as PV B-fragments
              mf[o] = ((cw >> kk) & 1u) ? (short)0 : (short)0x3F80;
            }
            s16x8 vb1[4], vb2[4];
#pragma unroll
            for (int db = 0; db < 4; ++db) {
              vb1[db] = *(const s16x8*)(sB + 4096 + (db * 64 + lane) * 16);
              vb2[db] = *(const s16x8*)(sB + 8192 + (db * 64 + lane) * 16);
            }
#pragma unroll
            for (int db = 0; db < 4; ++db) {
              a11[db] = __builtin_amdgcn_mfma_f32_16x16x32_bf16(wa1, vb1[db], a11[db], 0, 0, 0);
              a21[db] = __builtin_amdgcn_mfma_f32_16x16x32_bf16(wa1, vb2[db], a21[db], 0, 0, 0);
              a12[db] = __builtin_amdgcn_mfma_f32_16x16x32_bf16(wa2, vb1[db], a12[db], 0, 0, 0);
              a22[db] = __builtin_amdgcn_mfma_f32_16x16x32_bf16(wa2, vb2[db], a22[db], 0, 0, 0);
            }
            // normalizers on the MFMA pipe:
            za = __builtin_amdgcn_mfma_f32_16x16x32_bf16(wa1, ones, za, 0, 0, 0);
            t1a = __builtin_amdgcn_mfma_f32_16x16x32_bf16(wa1, mf, t1a, 0, 0, 0);
            t2a = __builtin_amdgcn_mfma_f32_16x16x32_bf16(wa2, mf, t2a, 0, 0, 0);
          }
          if (pf) {
            SWK(sbuf[(jt + 1) & 1], rk2);
            SWV(sbuf[(jt + 1) & 1], rv12, rv22);
          }
          __syncthreads();
        }
      }

      // za/t1a/t2a[e] already hold per-q-row (4g+e) sums — no reductions.
      const float* vs1 = vs + (size_t)b * D_ + h * DK_;
      const float* vs2 = vs + (size_t)(B_ + b) * D_ + h * DK_;

#pragma unroll
      for (int e = 0; e < 4; ++e) {
        const float iz = (za[e] > 0.f) ? (1.f / za[e]) : 0.f;  // row 0 -> 0
        const float f1 = iz;
        const float f2v = 0.5f * iz * iz;
        const float Z2 = (float)S_ + t1a[e] * f1 + t2a[e] * f2v;
        const float izz = 1.f / Z2;
        const float gg1 = f1 * izz;
        const float gg2 = f2v * izz;
        const float ggc = izz;
        int io = qw + 4 * g + e;
        bool zero = (io == 0);  // reference zeroes p row 0
        size_t ro = ((size_t)(b * S_) + io) * D_ + h * DK_;
#pragma unroll
        for (int db = 0; db < 4; ++db) {
          int dd = db * 16 + r;
          float o1 = a11[db][e] * gg1 + a12[db][e] * gg2 + vs1[dd] * ggc;
          float o2 = a21[db][e] * gg1 + a22[db][e] * gg2 + vs2[dd] * ggc;
          out1[ro + dd] = zero ? 0.f : o1;
          out2[ro + dd] = zero ? 0.f : o2;
        }
      }
    }
  }
#undef SLK
#undef SLV
#undef SWK
#undef SWV
#undef KFRAG
}

// ====================== FALLBACK (needs only 64KB ws) =======================

__global__ __launch_bounds__(256) void vsum_kernel(const float* __restrict__ v1,
                                                   const float* __restrict__ v2,
                                                   float* __restrict__ vs) {
  int bid = blockIdx.x;
  int sc = bid & 7, dc = (bid >> 3) & 3, b = bid >> 5;
  int d = dc * 256 + threadIdx.x;
  const float* p1 = v1 + ((size_t)b * S_ + sc * 128) * D_ + d;
  const float* p2 = v2 + ((size_t)b * S_ + sc * 128) * D_ + d;
  float s1 = 0.f, s2 = 0.f;
  for (int j = 0; j < 128; ++j) {
    s1 += p1[(size_t)j * D_];
    s2 += p2[(size_t)j * D_];
  }
  atomicAdd(&vs[b * D_ + d], s1);
  atomicAdd(&vs[B_ * D_ + b * D_ + d], s2);
}

__global__ __launch_bounds__(256) void dualattn_fallback(
    const float* __restrict__ q, const float* __restrict__ k,
    const float* __restrict__ v1, const float* __restrict__ v2,
    const int* __restrict__ cm, const float* __restrict__ vs,
    float* __restrict__ out) {
  const int bid = blockIdx.x;
  const int qt = bid & 15;
  const int h = (bid >> 4) & 15;
  const int b = bid >> 8;
  const int tid = threadIdx.x;
  const int wid = tid >> 6;
  const int lane = tid & 63;
  const int r = lane & 15;
  const int g = lane >> 4;
  const int qw = qt * 64 + wid * 16;
  const int iq = qw + r;

  __shared__ __align__(16) char kbuf[32 * 128];
  __shared__ __align__(16) char vtb1[64 * 64];
  __shared__ __align__(16) char vtb2[64 * 64];
  __shared__ unsigned cmw[32];

  {
    const int* cmb = cm + b * S_;
#pragma unroll
    for (int it = 0; it < 4; ++it) {
      int c = cmb[it * 256 + tid];
      unsigned long long m = __ballot(c == 1);
      if (lane == 0) {
        int w0 = (it * 256 + wid * 64) >> 5;
        cmw[w0] = (unsigned)m;
        cmw[w0 + 1] = (unsigned)(m >> 32);
      }
    }
  }

  s16x8 qf0, qf1;
  {
    const float* qp = q + ((size_t)(b * S_) + qw + r) * D_ + h * DK_;
#pragma unroll
    for (int e = 0; e < 8; ++e) qf0[e] = f2b(qp[8 * g + e] * 0.125f);
#pragma unroll
    for (int e = 0; e < 8; ++e) qf1[e] = f2b(qp[32 + 8 * g + e] * 0.125f);
  }

  const int njt = 2 * qt + 2;
  const float* kbase = k + (size_t)(b * S_) * D_ + h * DK_;
  const float* v1base = v1 + (size_t)(b * S_) * D_ + h * DK_;
  const float* v2base = v2 + (size_t)(b * S_) * D_ + h * DK_;
  const int srow = tid >> 3;
  const int sch = tid & 7;

  float m1 = -INFINITY, Z1 = 0.f;
  for (int jt = 0; jt < njt; ++jt) {
    const int jbase = jt * 32;
    __syncthreads();
    {
      const float* kr = kbase + (size_t)(jbase + srow) * D_ + sch * 8;
      s16x8 pk;
#pragma unroll
      for (int e = 0; e < 8; ++e) pk[e] = f2b(kr[e]);
      *(s16x8*)(kbuf + srow * 128 + ((sch ^ (srow & 7)) * 16)) = pk;
    }
    __syncthreads();
    if (jbase < qw + 16) {
#pragma unroll
      for (int sub = 0; sub < 2; ++sub) {
        const int jsb = jbase + sub * 16;
        if (jsb < qw + 16) {
          const int row = sub * 16 + r;
          s16x8 ka0 = *(const s16x8*)(kbuf + row * 128 + ((g ^ (row & 7)) * 16));
          s16x8 ka1 = *(const s16x8*)(kbuf + row * 128 + (((4 + g) ^ (row & 7)) * 16));
          f32x4 sv = {0.f, 0.f, 0.f, 0.f};
          sv = __builtin_amdgcn_mfma_f32_16x16x32_bf16(ka0, qf0, sv, 0, 0, 0);
          sv = __builtin_amdgcn_mfma_f32_16x16x32_bf16(ka1, qf1, sv, 0, 0, 0);
          float tm = m1;
#pragma unroll
          for (int e = 0; e < 4; ++e) {
            int j = jsb + 4 * g + e;
            if (j < iq) tm = fmaxf(tm, sv[e]);
          }
          if (tm > m1) { Z1 *= __expf(m1 - tm); m1 = tm; }
#pragma unroll
          for (int e = 0; e < 4; ++e) {
            int j = jsb + 4 * g + e;
            if (j < iq) Z1 += __expf(sv[e] - tm);
          }
        }
      }
    }
  }
#pragma unroll
  for (int off = 16; off < 64; off <<= 1) {
    float mo = __shfl_xor(m1, off);
    float zo = __shfl_xor(Z1, off);
    float mn = fmaxf(m1, mo);
    if (mn > -INFINITY) {
      Z1 = Z1 * __expf(m1 - mn) + zo * __expf(mo - mn);
      m1 = mn;
    }
  }
  float z1i;
  if (m1 > -INFINITY) { z1i = 1.f / Z1; }
  else { z1i = 0.f; m1 = 0.f; }

  f32x4 acc1[4], acc2[4];
#pragma unroll
  for (int d0 = 0; d0 < 4; ++d0) {
    acc1[d0] = (f32x4){0.f, 0.f, 0.f, 0.f};
    acc2[d0] = (f32x4){0.f, 0.f, 0.f, 0.f};
  }
  float wsum = 0.f;

  for (int jt = 0; jt < njt; ++jt) {
    const int jbase = jt * 32;
    __syncthreads();
    {
      const float* kr = kbase + (size_t)(jbase + srow) * D_ + sch * 8;
      s16x8 pk;
#pragma unroll
      for (int e = 0; e < 8; ++e) pk[e] = f2b(kr[e]);
      *(s16x8*)(kbuf + srow * 128 + ((sch ^ (srow & 7)) * 16)) = pk;
      const float* v1r = v1base + (size_t)(jbase + srow) * D_ + sch * 8;
      const float* v2r = v2base + (size_t)(jbase + srow) * D_ + sch * 8;
#pragma unroll
      for (int e = 0; e < 8; ++e) {
        int dd = sch * 8 + e;
        int off = dd * 64 + (((srow >> 2) ^ (dd & 7)) * 8) + (srow & 3) * 2;
        *(short*)(vtb1 + off) = f2b(v1r[e]);
        *(short*)(vtb2 + off) = f2b(v2r[e]);
      }
    }
    __syncthreads();
    if (jbase < qw + 16) {
      const unsigned cmword = cmw[jbase >> 5];
      float w[8];
#pragma unroll
      for (int sub = 0; sub < 2; ++sub) {
        const int jsb = jbase + sub * 16;
        if (jsb < qw + 16) {
          const int row = sub * 16 + r;
          s16x8 ka0 = *(const s16x8*)(kbuf + row * 128 + ((g ^ (row & 7)) * 16));
          s16x8 ka1 = *(const s16x8*)(kbuf + row * 128 + (((4 + g) ^ (row & 7)) * 16));
          f32x4 sv = {0.f, 0.f, 0.f, 0.f};
          sv = __builtin_amdgcn_mfma_f32_16x16x32_bf16(ka0, qf0, sv, 0, 0, 0);
          sv = __builtin_amdgcn_mfma_f32_16x16x32_bf16(ka1, qf1, sv, 0, 0, 0);
#pragma unroll
          for (int e = 0; e < 4; ++e) {
            int j = jsb + 4 * g + e;
            float x = 0.f;
            if (j < iq && !((cmword >> (j & 31)) & 1u)) {
              float p = __expf(sv[e] - m1) * z1i;
              x = __expf(p) - 1.f;
            }
            w[sub * 4 + e] = x;
            wsum += x;
          }
        } else {
#pragma unroll
          for (int e = 0; e < 4; ++e) w[sub * 4 + e] = 0.f;
        }
      }
      s16x8 wa;
#pragma unroll
      for (int e = 0; e < 8; ++e) wa[e] = f2b(w[e]);
#pragma unroll
      for (int db = 0; db < 4; ++db) {
        const int dd = db * 16 + r;
        const int off0 = dd * 64 + ((g ^ (dd & 7)) * 8);
        const int off1 = dd * 64 + (((4 + g) ^ (dd & 7)) * 8);
        s16x4 lo1 = *(const s16x4*)(vtb1 + off0);
        s16x4 hi1 = *(const s16x4*)(vtb1 + off1);
        s16x8 vb1 = __builtin_shufflevector(lo1, hi1, 0, 1, 2, 3, 4, 5, 6, 7);
        acc1[db] = __builtin_amdgcn_mfma_f32_16x16x32_bf16(wa, vb1, acc1[db], 0, 0, 0);
        s16x4 lo2 = *(const s16x4*)(vtb2 + off0);
        s16x4 hi2 = *(const s16x4*)(vtb2 + off1);
        s16x8 vb2 = __builtin_shufflevector(lo2, hi2, 0, 1, 2, 3, 4, 5, 6, 7);
        acc2[db] = __builtin_amdgcn_mfma_f32_16x16x32_bf16(wa, vb2, acc2[db], 0, 0, 0);
      }
    }
  }

  wsum += __shfl_xor(wsum, 16);
  wsum += __shfl_xor(wsum, 32);
  const float z2 = (float)S_ + wsum;

  float* out1 = out;
  float* out2 = out + (size_t)B_ * S_ * D_;
#pragma unroll
  for (int e = 0; e < 4; ++e) {
    float z2e = __shfl(z2, 4 * g + e);
    float inv = 1.f / z2e;
    int io = qw + 4 * g + e;
    bool zero = (io == 0);
    size_t ro = ((size_t)(b * S_) + io) * D_ + h * DK_;
#pragma unroll
    for (int db = 0; db < 4; ++db) {
      int dd = db * 16 + r;
      float c1 = vs[(size_t)b * D_ + h * DK_ + dd];
      float c2 = vs[(size_t)(B_ + b) * D_ + h * DK_ + dd];
      out1[ro + dd] = zero ? 0.f : (acc1[db][e] + c1) * inv;
      out2[ro + dd] = zero ? 0.f : (acc2[db][e] + c2) * inv;
    }
  }
}

// ============================================================================

extern "C" void kernel_launch(void* const* d_in, const int* in_sizes, int n_in,
                              void* d_out, int out_size, void* d_ws, size_t ws_size,
                              hipStream_t stream) {
  (void)in_sizes; (void)n_in; (void)out_size;
  const float* q = (const float*)d_in[0];
  const float* k = (const float*)d_in[1];
  const float* v1 = (const float*)d_in[2];
  const float* v2 = (const float*)d_in[3];
  const int* cm = (const int*)d_in[4];
  float* outp = (float*)d_out;

  const size_t VS_BYTES = 2 * B_ * D_ * sizeof(float);  // 64 KB
  const size_t CTR_BYTES = NQ * 64 * sizeof(unsigned);  // 8 queues, 256B apart
  const size_t FRAG_SHORTS = (size_t)BH_ * S_ * DK_;    // 8M shorts
  const size_t FRAG_BYTES = FRAG_SHORTS * 2;            // 16 MB
  const size_t NEED = VS_BYTES + CTR_BYTES + 3 * FRAG_BYTES;

  float* vs = (float*)d_ws;
  (void)hipMemsetAsync(d_ws, 0, VS_BYTES + CTR_BYTES, stream);

  if (ws_size >= NEED) {
    unsigned* counters = (unsigned*)((char*)d_ws + VS_BYTES);
    short* kb = (short*)((char*)d_ws + VS_BYTES + CTR_BYTES);
    short* v1f = kb + FRAG_SHORTS;
    short* v2f = v1f + FRAG_SHORTS;
    prep_k<<<B_ * (S_ / 16), 256, 0, stream>>>(k, kb);
    prep_v<<<B_ * H_ * 4, 256, 0, stream>>>(v1, v2, cm, v1f, v2f, vs);
    attn_series2s<<<NPERS, 256, 0, stream>>>(q, kb, v1f, v2f, cm, vs, counters,
                                             outp);
  } else {
    vsum_kernel<<<256, 256, 0, stream>>>(v1, v2, vs);
    dualattn_fallback<<<B_ * H_ * 16, 256, 0, stream>>>(q, k, v1, v2, cm, vs, outp);
  }
}

// Round 22
// 98.386 us; speedup vs baseline: 1.1755x; 1.0367x over previous
//
#include <hip/hip_runtime.h>
#include <hip/hip_bf16.h>

#define B_ 8
#define S_ 1024
#define D_ 1024
#define H_ 16
#define DK_ 64
#define BH_ (B_ * H_)
#define NQ 8
#define QTASK 256   // tasks per queue: 16 bh x 16 segs
#define NPERS 768

typedef float f32x4 __attribute__((ext_vector_type(4)));
typedef short s16x8 __attribute__((ext_vector_type(8)));
typedef short s16x4 __attribute__((ext_vector_type(4)));

// hardware transcendentals: v_exp_f32 computes 2^x
#define EXP2F(x) __builtin_amdgcn_exp2f(x)
#define LOG2E 1.44269504088896f

// fp32 -> bf16 (RNE), manual bit version (prep kernels)
static __device__ __forceinline__ short f2b(float f) {
  unsigned u = __builtin_bit_cast(unsigned, f);
  u = u + 0x7FFFu + ((u >> 16) & 1u);
  return (short)(u >> 16);
}
// fp32 -> bf16 via intrinsic
static __device__ __forceinline__ short f2bn(float f) {
  __hip_bfloat16 h = __float2bfloat16(f);
  return __builtin_bit_cast(short, h);
}

static __device__ __forceinline__ int slotf(int g, int e) {
  return (e < 4) ? (4 * g + e) : (16 + 4 * g + (e - 4));
}

// ============================ FUSED PREP KERNEL =============================
// bid <  512 : K f32 [b][s][d] -> bf16 [b][h][s][dk]
// bid < 1024 : V1/V2 -> bf16 B-fragment layout, cm-masked rows ZEROED,
//              + UNMASKED column sums (atomics into vs)
// bid == 1024: mfrag table — bf16 {0,1} mask fragments per (b, jt, g):
//              mfrag[((b*32+jt)*4+g)*8 + o] = cm[b][jt*32+slotf(g,o)] ? 0 : 1
__global__ __launch_bounds__(256) void prep_all(
    const float* __restrict__ k, const float* __restrict__ v1,
    const float* __restrict__ v2, const int* __restrict__ cm,
    short* __restrict__ kb, short* __restrict__ v1f, short* __restrict__ v2f,
    float* __restrict__ vs, short* __restrict__ mfrag) {
  const int bid = blockIdx.x;
  const int tid = threadIdx.x;

  if (bid < 512) {  // ---------------- K part
    const int s0 = (bid & 63) * 16;
    const int b = bid >> 6;
#pragma unroll
    for (int it = 0; it < 8; ++it) {
      int li = it * 256 + tid;
      int s = s0 + (li >> 7);
      int ch = li & 127;
      int h = ch >> 3;
      int dk0 = (ch & 7) * 8;
      const float* src = k + ((size_t)(b * S_ + s)) * D_ + ch * 8;
      s16x8 o;
#pragma unroll
      for (int e = 0; e < 8; ++e) o[e] = f2b(src[e]);
      *(s16x8*)(kb + ((size_t)((b * H_ + h) * S_ + s)) * DK_ + dk0) = o;
    }
  } else if (bid < 1024) {  // ---------------- V part
    const int b2 = bid - 512;
    const int sg = b2 & 3;
    const int h = (b2 >> 2) & 15;
    const int b = b2 >> 6;
    const int db = tid >> 6;
    const int lane = tid & 63;
    const int r = lane & 15;
    const int g = lane >> 4;
    const size_t inbase = (size_t)b * S_ * D_ + h * DK_ + db * 16 + r;
    const int* cmb = cm + b * S_;
    float s1 = 0.f, s2 = 0.f;
#pragma unroll
    for (int it = 0; it < 8; ++it) {
      int jt = sg * 8 + it;
      int j0 = jt * 32;
      s16x8 o1, o2;
#pragma unroll
      for (int e = 0; e < 8; ++e) {
        int j = j0 + slotf(g, e);
        float a = v1[inbase + (size_t)j * D_];
        float c = v2[inbase + (size_t)j * D_];
        s1 += a;  // baseline sums are over ALL rows (unmasked)
        s2 += c;
        bool msk = (cmb[j] == 1);
        o1[e] = msk ? (short)0 : f2b(a);
        o2[e] = msk ? (short)0 : f2b(c);
      }
      size_t off = (((size_t)((b * H_ + h) * 32 + jt) * 4 + db) * 64 + lane) * 8;
      *(s16x8*)(v1f + off) = o1;
      *(s16x8*)(v2f + off) = o2;
    }
    s1 += __shfl_xor(s1, 16);
    s1 += __shfl_xor(s1, 32);
    s2 += __shfl_xor(s2, 16);
    s2 += __shfl_xor(s2, 32);
    if (g == 0) {
      int dd = db * 16 + r;
      atomicAdd(&vs[(size_t)b * D_ + h * DK_ + dd], s1);
      atomicAdd(&vs[(size_t)(B_ + b) * D_ + h * DK_ + dd], s2);
    }
  } else {  // ---------------- mfrag table (8192 shorts)
#pragma unroll
    for (int i = 0; i < 32; ++i) {
      int idx = tid * 32 + i;
      int o = idx & 7;
      int g = (idx >> 3) & 3;
      int jt = (idx >> 5) & 31;
      int b = idx >> 10;
      int j = jt * 32 + slotf(g, o);
      mfrag[idx] = (cm[b * S_ + j] == 1) ? (short)0 : (short)0x3F80;
    }
  }
}

// ============================ MAIN ATTENTION ================================
// R21 post-mortem: VALU still leads (43%). This round: (1) mf fragments
// precomputed into a 16KB L2-resident table (removes per-task ballot block +
// cmw LDS + 8 selects/tile -> one 16B broadcast load); (2) preps fused into
// one kernel (saves ~2 launch overheads). Scheduling/math = R21 unchanged
// (per-XCD seg-major queues, 2-term series, normalizers on MFMA pipe).
__global__ __launch_bounds__(256, 3) void attn_series2t(
    const float* __restrict__ q, const short* __restrict__ kb,
    const short* __restrict__ v1f, const short* __restrict__ v2f,
    const short* __restrict__ mfrag, const float* __restrict__ vs,
    unsigned* __restrict__ counters, float* __restrict__ out) {
  const int tid = threadIdx.x;
  const int wid = tid >> 6;
  const int lane = tid & 63;
  const int r = lane & 15;
  const int g = lane >> 4;

  // physical XCD id; perf hint only (work-stealing keeps correctness)
  unsigned xcc = 0;
  asm volatile("s_getreg_b32 %0, hwreg(HW_REG_XCC_ID)" : "=s"(xcc));
  const int xq = (int)(xcc & 7u);

  // LDS: 2 buffers x {K 4KB (swizzled) | V1 4KB | V2 4KB}
  __shared__ __align__(16) char sbuf[2][12288];
  __shared__ int taskS;

  const int srow = tid >> 3;  // staging K row 0..31
  const int sch = tid & 7;    // staging K chunk 0..7

#define SLK(reg, jtv) reg = *(const s16x8*)(kbh + (size_t)(jtv)*2048 + tid * 8);
#define SLV(d1, d2, jtv)                                           \
  {                                                                \
    d1 = *(const s16x8*)(v1bh + (size_t)(jtv)*2048 + tid * 8);     \
    d2 = *(const s16x8*)(v2bh + (size_t)(jtv)*2048 + tid * 8);     \
  }
#define SWK(buf, reg) \
  *(s16x8*)((buf) + srow * 128 + ((sch ^ (srow & 7)) * 16)) = reg;
#define SWV(buf, d1, d2)                        \
  {                                             \
    *(s16x8*)((buf) + 4096 + tid * 16) = d1;    \
    *(s16x8*)((buf) + 8192 + tid * 16) = d2;    \
  }
#define KFRAG(sK, row, quad) \
  (*(const s16x8*)((sK) + (row)*128 + (((quad) ^ ((row)&7)) * 16)))

  s16x8 ones;
#pragma unroll
  for (int e = 0; e < 8; ++e) ones[e] = (short)0x3F80;  // bf16 1.0

  float* out1 = out;
  float* out2 = out + (size_t)B_ * S_ * D_;

  for (int qi = 0; qi < NQ; ++qi) {
    const int qq = (xq + qi) & 7;
    for (;;) {
      __syncthreads();  // previous task's LDS reads + taskS read complete
      if (tid == 0) taskS = (int)atomicAdd(&counters[qq * 64], 1u);
      __syncthreads();
      const int task = taskS;
      if (task >= QTASK) break;

      // seg-major (LPT): tasks 0..15 are seg 15 across bh, then seg 14...
      const int seg = 15 - (task >> 4);
      const int bh = (task & 15) * 8 + qq;
      const int b = bh >> 4, h = bh & 15;

      const int qw = seg * 64 + wid * 16;  // this wave's 16 q-rows
      const int iq = qw + r;
      const int njt = 2 * seg + 2;         // 32-wide tiles (block-uniform)

      // Q fragments, pre-scaled by log2e/sqrt(dk) -> log2-domain scores
      const float qscale = 0.125f * LOG2E;
      s16x8 qf0, qf1;
      {
        const float* qp = q + ((size_t)(b * S_ + qw + r)) * D_ + h * DK_;
#pragma unroll
        for (int e = 0; e < 8; ++e) qf0[e] = f2bn(qp[8 * g + e] * qscale);
#pragma unroll
        for (int e = 0; e < 8; ++e) qf1[e] = f2bn(qp[32 + 8 * g + e] * qscale);
      }

      const short* kbh = kb + (size_t)bh * S_ * DK_;
      const short* v1bh = v1f + (size_t)bh * 32 * 2048;
      const short* v2bh = v2f + (size_t)bh * 32 * 2048;
      const short* mfb = mfrag + ((size_t)b * 32 * 4 + g) * 8;

      // accumulators: PV terms k=1..2 for V1,V2 + normalizers (MFMA-summed)
      f32x4 a11[4], a12[4], a21[4], a22[4];
#pragma unroll
      for (int d0 = 0; d0 < 4; ++d0) {
        a11[d0] = (f32x4){0.f, 0.f, 0.f, 0.f};
        a12[d0] = (f32x4){0.f, 0.f, 0.f, 0.f};
        a21[d0] = (f32x4){0.f, 0.f, 0.f, 0.f};
        a22[d0] = (f32x4){0.f, 0.f, 0.f, 0.f};
      }
      f32x4 za = {0.f, 0.f, 0.f, 0.f};   // Z1 per q-row 4g+e
      f32x4 t1a = {0.f, 0.f, 0.f, 0.f};  // T1
      f32x4 t2a = {0.f, 0.f, 0.f, 0.f};  // T2

      {
        s16x8 rk, rv1, rv2;
        SLK(rk, 0);
        SLV(rv1, rv2, 0);
        SWK(sbuf[0], rk);
        SWV(sbuf[0], rv1, rv2);
        __syncthreads();  // buf0 ready
        for (int jt = 0; jt < njt; ++jt) {
          const int jb = jt * 32;
          const char* sB = sbuf[jt & 1];
          const bool pf = (jt + 1 < njt);
          s16x8 rk2, rv12, rv22;
          if (pf) {
            SLK(rk2, jt + 1);
            SLV(rv12, rv22, jt + 1);
          }
          if (jb < qw + 16) {  // tile has work for this wave
            s16x8 mf = *(const s16x8*)(mfb + (size_t)jt * 32);
            s16x8 k00 = KFRAG(sB, r, g);
            s16x8 k01 = KFRAG(sB, r, 4 + g);
            s16x8 k10 = KFRAG(sB, 16 + r, g);
            s16x8 k11 = KFRAG(sB, 16 + r, 4 + g);
            f32x4 s0 = {0.f, 0.f, 0.f, 0.f}, s1 = {0.f, 0.f, 0.f, 0.f};
            s0 = __builtin_amdgcn_mfma_f32_16x16x32_bf16(k00, qf0, s0, 0, 0, 0);
            s0 = __builtin_amdgcn_mfma_f32_16x16x32_bf16(k01, qf1, s0, 0, 0, 0);
            s1 = __builtin_amdgcn_mfma_f32_16x16x32_bf16(k10, qf0, s1, 0, 0, 0);
            s1 = __builtin_amdgcn_mfma_f32_16x16x32_bf16(k11, qf1, s1, 0, 0, 0);
            const bool cb = (jb + 32 > qw);  // tile crosses diagonal
            float w1[8], w2[8];
#pragma unroll
            for (int s2 = 0; s2 < 2; ++s2) {
              f32x4 sv = s2 ? s1 : s0;
#pragma unroll
              for (int e = 0; e < 4; ++e) {
                float pe = EXP2F(sv[e]);  // exp(s_j), unnormalized
                if (cb) {
                  int j = jb + s2 * 16 + 4 * g + e;
                  pe = (j < iq) ? pe : 0.f;  // causal (first softmax)
                }
                int o = s2 * 4 + e;
                w1[o] = pe;
                w2[o] = pe * pe;
              }
            }
            s16x8 wa1, wa2;
#pragma unroll
            for (int o = 0; o < 8; ++o) {
              wa1[o] = f2bn(w1[o]);
              wa2[o] = f2bn(w2[o]);
            }
            s16x8 vb1[4], vb2[4];
#pragma unroll
            for (int db = 0; db < 4; ++db) {
              vb1[db] = *(const s16x8*)(sB + 4096 + (db * 64 + lane) * 16);
              vb2[db] = *(const s16x8*)(sB + 8192 + (db * 64 + lane) * 16);
            }
#pragma unroll
            for (int db = 0; db < 4; ++db) {
              a11[db] = __builtin_amdgcn_mfma_f32_16x16x32_bf16(wa1, vb1[db], a11[db], 0, 0, 0);
              a21[db] = __builtin_amdgcn_mfma_f32_16x16x32_bf16(wa1, vb2[db], a21[db], 0, 0, 0);
              a12[db] = __builtin_amdgcn_mfma_f32_16x16x32_bf16(wa2, vb1[db], a12[db], 0, 0, 0);
              a22[db] = __builtin_amdgcn_mfma_f32_16x16x32_bf16(wa2, vb2[db], a22[db], 0, 0, 0);
            }
            // normalizers on the MFMA pipe:
            za = __builtin_amdgcn_mfma_f32_16x16x32_bf16(wa1, ones, za, 0, 0, 0);
            t1a = __builtin_amdgcn_mfma_f32_16x16x32_bf16(wa1, mf, t1a, 0, 0, 0);
            t2a = __builtin_amdgcn_mfma_f32_16x16x32_bf16(wa2, mf, t2a, 0, 0, 0);
          }
          if (pf) {
            SWK(sbuf[(jt + 1) & 1], rk2);
            SWV(sbuf[(jt + 1) & 1], rv12, rv22);
          }
          __syncthreads();
        }
      }

      // za/t1a/t2a[e] already hold per-q-row (4g+e) sums — no reductions.
      const float* vs1 = vs + (size_t)b * D_ + h * DK_;
      const float* vs2 = vs + (size_t)(B_ + b) * D_ + h * DK_;

#pragma unroll
      for (int e = 0; e < 4; ++e) {
        const float iz = (za[e] > 0.f) ? (1.f / za[e]) : 0.f;  // row 0 -> 0
        const float f1 = iz;
        const float f2v = 0.5f * iz * iz;
        const float Z2 = (float)S_ + t1a[e] * f1 + t2a[e] * f2v;
        const float izz = 1.f / Z2;
        const float gg1 = f1 * izz;
        const float gg2 = f2v * izz;
        const float ggc = izz;
        int io = qw + 4 * g + e;
        bool zero = (io == 0);  // reference zeroes p row 0
        size_t ro = ((size_t)(b * S_) + io) * D_ + h * DK_;
#pragma unroll
        for (int db = 0; db < 4; ++db) {
          int dd = db * 16 + r;
          float o1 = a11[db][e] * gg1 + a12[db][e] * gg2 + vs1[dd] * ggc;
          float o2 = a21[db][e] * gg1 + a22[db][e] * gg2 + vs2[dd] * ggc;
          out1[ro + dd] = zero ? 0.f : o1;
          out2[ro + dd] = zero ? 0.f : o2;
        }
      }
    }
  }
#undef SLK
#undef SLV
#undef SWK
#undef SWV
#undef KFRAG
}

// ====================== FALLBACK (needs only 64KB ws) =======================

__global__ __launch_bounds__(256) void vsum_kernel(const float* __restrict__ v1,
                                                   const float* __restrict__ v2,
                                                   float* __restrict__ vs) {
  int bid = blockIdx.x;
  int sc = bid & 7, dc = (bid >> 3) & 3, b = bid >> 5;
  int d = dc * 256 + threadIdx.x;
  const float* p1 = v1 + ((size_t)b * S_ + sc * 128) * D_ + d;
  const float* p2 = v2 + ((size_t)b * S_ + sc * 128) * D_ + d;
  float s1 = 0.f, s2 = 0.f;
  for (int j = 0; j < 128; ++j) {
    s1 += p1[(size_t)j * D_];
    s2 += p2[(size_t)j * D_];
  }
  atomicAdd(&vs[b * D_ + d], s1);
  atomicAdd(&vs[B_ * D_ + b * D_ + d], s2);
}

__global__ __launch_bounds__(256) void dualattn_fallback(
    const float* __restrict__ q, const float* __restrict__ k,
    const float* __restrict__ v1, const float* __restrict__ v2,
    const int* __restrict__ cm, const float* __restrict__ vs,
    float* __restrict__ out) {
  const int bid = blockIdx.x;
  const int qt = bid & 15;
  const int h = (bid >> 4) & 15;
  const int b = bid >> 8;
  const int tid = threadIdx.x;
  const int wid = tid >> 6;
  const int lane = tid & 63;
  const int r = lane & 15;
  const int g = lane >> 4;
  const int qw = qt * 64 + wid * 16;
  const int iq = qw + r;

  __shared__ __align__(16) char kbuf[32 * 128];
  __shared__ __align__(16) char vtb1[64 * 64];
  __shared__ __align__(16) char vtb2[64 * 64];
  __shared__ unsigned cmw[32];

  {
    const int* cmb = cm + b * S_;
#pragma unroll
    for (int it = 0; it < 4; ++it) {
      int c = cmb[it * 256 + tid];
      unsigned long long m = __ballot(c == 1);
      if (lane == 0) {
        int w0 = (it * 256 + wid * 64) >> 5;
        cmw[w0] = (unsigned)m;
        cmw[w0 + 1] = (unsigned)(m >> 32);
      }
    }
  }

  s16x8 qf0, qf1;
  {
    const float* qp = q + ((size_t)(b * S_) + qw + r) * D_ + h * DK_;
#pragma unroll
    for (int e = 0; e < 8; ++e) qf0[e] = f2b(qp[8 * g + e] * 0.125f);
#pragma unroll
    for (int e = 0; e < 8; ++e) qf1[e] = f2b(qp[32 + 8 * g + e] * 0.125f);
  }

  const int njt = 2 * qt + 2;
  const float* kbase = k + (size_t)(b * S_) * D_ + h * DK_;
  const float* v1base = v1 + (size_t)(b * S_) * D_ + h * DK_;
  const float* v2base = v2 + (size_t)(b * S_) * D_ + h * DK_;
  const int srow = tid >> 3;
  const int sch = tid & 7;

  float m1 = -INFINITY, Z1 = 0.f;
  for (int jt = 0; jt < njt; ++jt) {
    const int jbase = jt * 32;
    __syncthreads();
    {
      const float* kr = kbase + (size_t)(jbase + srow) * D_ + sch * 8;
      s16x8 pk;
#pragma unroll
      for (int e = 0; e < 8; ++e) pk[e] = f2b(kr[e]);
      *(s16x8*)(kbuf + srow * 128 + ((sch ^ (srow & 7)) * 16)) = pk;
    }
    __syncthreads();
    if (jbase < qw + 16) {
#pragma unroll
      for (int sub = 0; sub < 2; ++sub) {
        const int jsb = jbase + sub * 16;
        if (jsb < qw + 16) {
          const int row = sub * 16 + r;
          s16x8 ka0 = *(const s16x8*)(kbuf + row * 128 + ((g ^ (row & 7)) * 16));
          s16x8 ka1 = *(const s16x8*)(kbuf + row * 128 + (((4 + g) ^ (row & 7)) * 16));
          f32x4 sv = {0.f, 0.f, 0.f, 0.f};
          sv = __builtin_amdgcn_mfma_f32_16x16x32_bf16(ka0, qf0, sv, 0, 0, 0);
          sv = __builtin_amdgcn_mfma_f32_16x16x32_bf16(ka1, qf1, sv, 0, 0, 0);
          float tm = m1;
#pragma unroll
          for (int e = 0; e < 4; ++e) {
            int j = jsb + 4 * g + e;
            if (j < iq) tm = fmaxf(tm, sv[e]);
          }
          if (tm > m1) { Z1 *= __expf(m1 - tm); m1 = tm; }
#pragma unroll
          for (int e = 0; e < 4; ++e) {
            int j = jsb + 4 * g + e;
            if (j < iq) Z1 += __expf(sv[e] - tm);
          }
        }
      }
    }
  }
#pragma unroll
  for (int off = 16; off < 64; off <<= 1) {
    float mo = __shfl_xor(m1, off);
    float zo = __shfl_xor(Z1, off);
    float mn = fmaxf(m1, mo);
    if (mn > -INFINITY) {
      Z1 = Z1 * __expf(m1 - mn) + zo * __expf(mo - mn);
      m1 = mn;
    }
  }
  float z1i;
  if (m1 > -INFINITY) { z1i = 1.f / Z1; }
  else { z1i = 0.f; m1 = 0.f; }

  f32x4 acc1[4], acc2[4];
#pragma unroll
  for (int d0 = 0; d0 < 4; ++d0) {
    acc1[d0] = (f32x4){0.f, 0.f, 0.f, 0.f};
    acc2[d0] = (f32x4){0.f, 0.f, 0.f, 0.f};
  }
  float wsum = 0.f;

  for (int jt = 0; jt < njt; ++jt) {
    const int jbase = jt * 32;
    __syncthreads();
    {
      const float* kr = kbase + (size_t)(jbase + srow) * D_ + sch * 8;
      s16x8 pk;
#pragma unroll
      for (int e = 0; e < 8; ++e) pk[e] = f2b(kr[e]);
      *(s16x8*)(kbuf + srow * 128 + ((sch ^ (srow & 7)) * 16)) = pk;
      const float* v1r = v1base + (size_t)(jbase + srow) * D_ + sch * 8;
      const float* v2r = v2base + (size_t)(jbase + srow) * D_ + sch * 8;
#pragma unroll
      for (int e = 0; e < 8; ++e) {
        int dd = sch * 8 + e;
        int off = dd * 64 + (((srow >> 2) ^ (dd & 7)) * 8) + (srow & 3) * 2;
        *(short*)(vtb1 + off) = f2b(v1r[e]);
        *(short*)(vtb2 + off) = f2b(v2r[e]);
      }
    }
    __syncthreads();
    if (jbase < qw + 16) {
      const unsigned cmword = cmw[jbase >> 5];
      float w[8];
#pragma unroll
      for (int sub = 0; sub < 2; ++sub) {
        const int jsb = jbase + sub * 16;
        if (jsb < qw + 16) {
          const int row = sub * 16 + r;
          s16x8 ka0 = *(const s16x8*)(kbuf + row * 128 + ((g ^ (row & 7)) * 16));
          s16x8 ka1 = *(const s16x8*)(kbuf + row * 128 + (((4 + g) ^ (row & 7)) * 16));
          f32x4 sv = {0.f, 0.f, 0.f, 0.f};
          sv = __builtin_amdgcn_mfma_f32_16x16x32_bf16(ka0, qf0, sv, 0, 0, 0);
          sv = __builtin_amdgcn_mfma_f32_16x16x32_bf16(ka1, qf1, sv, 0, 0, 0);
#pragma unroll
          for (int e = 0; e < 4; ++e) {
            int j = jsb + 4 * g + e;
            float x = 0.f;
            if (j < iq && !((cmword >> (j & 31)) & 1u)) {
              float p = __expf(sv[e] - m1) * z1i;
              x = __expf(p) - 1.f;
            }
            w[sub * 4 + e] = x;
            wsum += x;
          }
        } else {
#pragma unroll
          for (int e = 0; e < 4; ++e) w[sub * 4 + e] = 0.f;
        }
      }
      s16x8 wa;
#pragma unroll
      for (int e = 0; e < 8; ++e) wa[e] = f2b(w[e]);
#pragma unroll
      for (int db = 0; db < 4; ++db) {
        const int dd = db * 16 + r;
        const int off0 = dd * 64 + ((g ^ (dd & 7)) * 8);
        const int off1 = dd * 64 + (((4 + g) ^ (dd & 7)) * 8);
        s16x4 lo1 = *(const s16x4*)(vtb1 + off0);
        s16x4 hi1 = *(const s16x4*)(vtb1 + off1);
        s16x8 vb1 = __builtin_shufflevector(lo1, hi1, 0, 1, 2, 3, 4, 5, 6, 7);
        acc1[db] = __builtin_amdgcn_mfma_f32_16x16x32_bf16(wa, vb1, acc1[db], 0, 0, 0);
        s16x4 lo2 = *(const s16x4*)(vtb2 + off0);
        s16x4 hi2 = *(const s16x4*)(vtb2 + off1);
        s16x8 vb2 = __builtin_shufflevector(lo2, hi2, 0, 1, 2, 3, 4, 5, 6, 7);
        acc2[db] = __builtin_amdgcn_mfma_f32_16x16x32_bf16(wa, vb2, acc2[db], 0, 0, 0);
      }
    }
  }

  wsum += __shfl_xor(wsum, 16);
  wsum += __shfl_xor(wsum, 32);
  const float z2 = (float)S_ + wsum;

  float* out1 = out;
  float* out2 = out + (size_t)B_ * S_ * D_;
#pragma unroll
  for (int e = 0; e < 4; ++e) {
    float z2e = __shfl(z2, 4 * g + e);
    float inv = 1.f / z2e;
    int io = qw + 4 * g + e;
    bool zero = (io == 0);
    size_t ro = ((size_t)(b * S_) + io) * D_ + h * DK_;
#pragma unroll
    for (int db = 0; db < 4; ++db) {
      int dd = db * 16 + r;
      float c1 = vs[(size_t)b * D_ + h * DK_ + dd];
      float c2 = vs[(size_t)(B_ + b) * D_ + h * DK_ + dd];
      out1[ro + dd] = zero ? 0.f : (acc1[db][e] + c1) * inv;
      out2[ro + dd] = zero ? 0.f : (acc2[db][e] + c2) * inv;
    }
  }
}

// ============================================================================

extern "C" void kernel_launch(void* const* d_in, const int* in_sizes, int n_in,
                              void* d_out, int out_size, void* d_ws, size_t ws_size,
                              hipStream_t stream) {
  (void)in_sizes; (void)n_in; (void)out_size;
  const float* q = (const float*)d_in[0];
  const float* k = (const float*)d_in[1];
  const float* v1 = (const float*)d_in[2];
  const float* v2 = (const float*)d_in[3];
  const int* cm = (const int*)d_in[4];
  float* outp = (float*)d_out;

  const size_t VS_BYTES = 2 * B_ * D_ * sizeof(float);  // 64 KB
  const size_t CTR_BYTES = NQ * 64 * sizeof(unsigned);  // 8 queues, 256B apart
  const size_t MF_BYTES = 8192 * sizeof(short);         // 16 KB mfrag table
  const size_t FRAG_SHORTS = (size_t)BH_ * S_ * DK_;    // 8M shorts
  const size_t FRAG_BYTES = FRAG_SHORTS * 2;            // 16 MB
  const size_t NEED = VS_BYTES + CTR_BYTES + MF_BYTES + 3 * FRAG_BYTES;

  float* vs = (float*)d_ws;
  (void)hipMemsetAsync(d_ws, 0, VS_BYTES + CTR_BYTES, stream);

  if (ws_size >= NEED) {
    unsigned* counters = (unsigned*)((char*)d_ws + VS_BYTES);
    short* mfrag = (short*)((char*)d_ws + VS_BYTES + CTR_BYTES);
    short* kb = (short*)((char*)d_ws + VS_BYTES + CTR_BYTES + MF_BYTES);
    short* v1f = kb + FRAG_SHORTS;
    short* v2f = v1f + FRAG_SHORTS;
    prep_all<<<1025, 256, 0, stream>>>(k, v1, v2, cm, kb, v1f, v2f, vs, mfrag);
    attn_series2t<<<NPERS, 256, 0, stream>>>(q, kb, v1f, v2f, mfrag, vs,
                                             counters, outp);
  } else {
    vsum_kernel<<<256, 256, 0, stream>>>(v1, v2, vs);
    dualattn_fallback<<<B_ * H_ * 16, 256, 0, stream>>>(q, k, v1, v2, cm, vs, outp);
  }
}